// Round 8
// baseline (167.882 us; speedup 1.0000x reference)
//
#include <hip/hip_runtime.h>
#include <stdint.h>

#define S_LEN 2048
#define DMODEL 1024
#define NHEAD 16
#define DK 64
#define BATCH 2

typedef __attribute__((ext_vector_type(8))) short bf16x8;
typedef __attribute__((ext_vector_type(4))) float f32x4;
typedef __attribute__((ext_vector_type(16))) float f32x16;
typedef __attribute__((ext_vector_type(2))) unsigned int uint2v;

__device__ __forceinline__ unsigned short f2bf(float f) {
  union { float f; unsigned u; } x; x.f = f;
  unsigned u = x.u;
  return (unsigned short)((u + 0x7fffu + ((u >> 16) & 1u)) >> 16);
}

__device__ __forceinline__ uint cvt_pk_bf16(float a, float b) {
  uint r;
  asm("v_cvt_pk_bf16_f32 %0, %1, %2" : "=v"(r) : "v"(a), "v"(b));
  return r;
}

// (d,s) = permlane32_swap(a,b): lanes<32: d=own a, s=partner's a;
//         lanes>=32: d=partner's b, s=own b.
__device__ __forceinline__ uint2v permswap(uint a, uint b) {
#if __has_builtin(__builtin_amdgcn_permlane32_swap)
  auto rr = __builtin_amdgcn_permlane32_swap(a, b, false, false);
  uint2v r; r.x = rr[0]; r.y = rr[1];
  return r;
#else
  uint ax = __shfl_xor(a, 32), bx = __shfl_xor(b, 32);
  int hi = (threadIdx.x & 63) >> 5;
  uint2v r; r.x = hi ? bx : a; r.y = hi ? b : ax;
  return r;
#endif
}

__device__ __forceinline__ void gload_lds16(const void* g, void* l) {
  __builtin_amdgcn_global_load_lds(
      (const __attribute__((address_space(1))) unsigned int*)g,
      (__attribute__((address_space(3))) unsigned int*)l, 16, 0, 0);
}

// Q scale: 1/sqrt(64) * log2(e)  (exp2-domain softmax)
#define QSCALE 0.18033688011112042f

// ------------- cast fp32 -> bf16 (x, weights) + RoPE table (fused) -------
__global__ __launch_bounds__(256) void cast_inputs(
    const float4* __restrict__ x,
    const float4* __restrict__ wq, const float4* __restrict__ wk,
    const float4* __restrict__ wv, const float4* __restrict__ wo,
    ushort4* __restrict__ xb, ushort4* __restrict__ wqkvb, ushort4* __restrict__ wob,
    const int* __restrict__ pos, float2* __restrict__ rope)
{
  int i = blockIdx.x * 256 + threadIdx.x;
  const int NCAST = (1 << 21);
  if (i < NCAST) {
    float4 v; ushort4* dst;
    if (i < (1 << 20)) {
      v = x[i]; dst = xb + i;
    } else {
      int j = i - (1 << 20);
      int wsel = j >> 18;
      int o = j & ((1 << 18) - 1);
      const float4* src = (wsel == 0) ? wq : (wsel == 1) ? wk : (wsel == 2) ? wv : wo;
      v = src[o];
      dst = (wsel < 3) ? (wqkvb + ((size_t)wsel << 18) + o) : (wob + o);
    }
    ushort4 r;
    r.x = f2bf(v.x); r.y = f2bf(v.y); r.z = f2bf(v.z); r.w = f2bf(v.w);
    *dst = r;
  } else {
    int idx = i - NCAST;
    if (idx < 4096 * 32) {
      int ps = idx >> 5;
      int fi = idx & 31;
      float p = (float)pos[ps];
      float freq = exp2f(-(float)fi * 0.41524101186092096f);
      float ang = p * freq;
      rope[idx] = make_float2(cosf(ang), sinf(ang));
    }
  }
}

// ---------------- GEMM (bf16 in, fp32 acc), B^T weights -------------------
template<int EPI>
__global__ __launch_bounds__(256) void gemm_bt(
    const ushort* __restrict__ A, const ushort* __restrict__ Bw,
    const float2* __restrict__ rope,
    ushort* __restrict__ Qb, ushort* __restrict__ Kb, ushort* __restrict__ Vg,
    float* __restrict__ Out)
{
  constexpr int Kdim = 1024;
  __shared__ ushort At[128 * 64];
  __shared__ ushort Bt[128 * 64];
  const int bm = blockIdx.x & 31;
  const int bn = blockIdx.x >> 5;
  const int tid = threadIdx.x;
  const int w = tid >> 6, lane = tid & 63;
  const int wr = w >> 1, wc = w & 1;
  const int lrow = lane >> 3;
  const int lch = lane & 7;

  f32x4 acc[4][4];
#pragma unroll
  for (int i = 0; i < 4; ++i)
#pragma unroll
    for (int j = 0; j < 4; ++j) acc[i][j] = (f32x4){0.f, 0.f, 0.f, 0.f};

  const size_t abase = (size_t)(bm * 128) * Kdim;
  const size_t bbase = (size_t)(bn * 128) * Kdim;

  for (int kt = 0; kt < Kdim / 64; ++kt) {
#pragma unroll
    for (int inst = 0; inst < 4; ++inst) {
      int r = w * 32 + inst * 8 + lrow;
      int gc = lch ^ (r & 7);
      gload_lds16(A + abase + (size_t)r * Kdim + kt * 64 + gc * 8,
                  &At[(w * 32 + inst * 8) * 64]);
      gload_lds16(Bw + bbase + (size_t)r * Kdim + kt * 64 + gc * 8,
                  &Bt[(w * 32 + inst * 8) * 64]);
    }
    __syncthreads();
    __builtin_amdgcn_s_setprio(1);
#pragma unroll
    for (int kk = 0; kk < 2; ++kk) {
      bf16x8 af[4], bfv[4];
      int ch = kk * 4 + (lane >> 4);
#pragma unroll
      for (int fm = 0; fm < 4; ++fm) {
        int row = wr * 64 + fm * 16 + (lane & 15);
        af[fm] = *(const bf16x8*)&At[row * 64 + ((ch ^ (row & 7)) << 3)];
      }
#pragma unroll
      for (int fn = 0; fn < 4; ++fn) {
        int row = wc * 64 + fn * 16 + (lane & 15);
        bfv[fn] = *(const bf16x8*)&Bt[row * 64 + ((ch ^ (row & 7)) << 3)];
      }
#pragma unroll
      for (int fm = 0; fm < 4; ++fm)
#pragma unroll
        for (int fn = 0; fn < 4; ++fn)
          acc[fm][fn] = __builtin_amdgcn_mfma_f32_16x16x32_bf16(
              af[fm], bfv[fn], acc[fm][fn], 0, 0, 0);
    }
    __builtin_amdgcn_s_setprio(0);
    __syncthreads();
  }

  if constexpr (EPI == 0) {
    const int sel = bn >> 3;            // 0=Q 1=K 2=V (block-uniform)
    if (sel == 2) {
      // V: transposed global layout [bh][d][s]
#pragma unroll
      for (int fn = 0; fn < 4; ++fn) {
        int gn = bn * 128 + wc * 64 + fn * 16 + (lane & 15);
        int col = gn & 1023;
        int h = col >> 6, d = col & 63;
#pragma unroll
        for (int fm = 0; fm < 4; ++fm) {
          int gm0 = bm * 128 + wr * 64 + fm * 16 + ((lane >> 4) << 2);
          int b = gm0 >> 11, s0 = gm0 & 2047;
          uint lo = (uint)f2bf(acc[fm][fn][0]) | ((uint)f2bf(acc[fm][fn][1]) << 16);
          uint hi2 = (uint)f2bf(acc[fm][fn][2]) | ((uint)f2bf(acc[fm][fn][3]) << 16);
          uint2 val; val.x = lo; val.y = hi2;
          *(uint2*)(Vg + ((size_t)((b * NHEAD + h) * DK + d) * S_LEN) + s0) = val;
        }
      }
    } else {
      ushort* dst0 = (sel == 0) ? Qb : Kb;
#pragma unroll
      for (int fn = 0; fn < 4; ++fn) {
        int gn = bn * 128 + wc * 64 + fn * 16 + (lane & 15);
        int col = gn & 1023;
        int h = col >> 6, d = col & 63;
#pragma unroll
        for (int fm = 0; fm < 4; ++fm) {
          int gm0 = bm * 128 + wr * 64 + fm * 16 + ((lane >> 4) << 2);
#pragma unroll
          for (int j = 0; j < 4; ++j) {
            int gm = gm0 + j;
            float v = acc[fm][fn][j];
            float p = __shfl_xor(v, 1);
            float2 cs = rope[gm * 32 + (d >> 1)];
            float r = (d & 1) ? (v * cs.x + p * cs.y) : (v * cs.x - p * cs.y);
            if (sel == 0) r *= QSCALE;  // 1/8 * log2(e): exp2-domain softmax
            int b = gm >> 11, s = gm & 2047;
            dst0[((size_t)(b * NHEAD + h) * S_LEN + s) * DK + d] = f2bf(r);
          }
        }
      }
    }
  } else {
#pragma unroll
    for (int fn = 0; fn < 4; ++fn) {
      int gn = bn * 128 + wc * 64 + fn * 16 + (lane & 15);
#pragma unroll
      for (int fm = 0; fm < 4; ++fm) {
        int gm0 = bm * 128 + wr * 64 + fm * 16 + ((lane >> 4) << 2);
#pragma unroll
        for (int j = 0; j < 4; ++j)
          Out[(size_t)(gm0 + j) * 1024 + gn] = acc[fm][fn][j];
      }
    }
  }
}

// -------- causal flash attention: barrier-free, L2-direct, 32x32 MFMA ------
// grid 1024 = 8 XCD-chunks x (4 bh x 32 qt, heavy qt first); block 256 = 4
// waves over ONE 64-row q-tile. Waves {0,1}: rows [0,32)/[32,64) x EVEN kv
// tiles; waves {2,3}: same rows x ODD kv tiles. K/V read directly from L2
// (4 heads/XCD = 2 MB, L2-resident) — no staging, no barriers in main loop.
// Parity partials merged once at the end via LDS.
__global__ __launch_bounds__(256, 2) void attn_kernel(
    const ushort* __restrict__ Qb, const ushort* __restrict__ Kb,
    const ushort* __restrict__ Vg, ushort* __restrict__ Ob)
{
  __shared__ float xbuf[2][64][34];     // parity-partner (oacc, m, l)
  __shared__ ushort oscratch[2][2048];  // per-store-wave 4 KB transpose buf
  const int tid = threadIdx.x;
  const int w = tid >> 6, lane = tid & 63;
  const int hi = lane >> 5, q = lane & 31;
  const int rowhalf = w & 1, par = w >> 1;
  const int bid = blockIdx.x;
  const int xcd = bid & 7, idx = bid >> 3;
  const int bh = xcd * 4 + (idx >> 5);
  const int qt = 31 - (idx & 31);       // heavy q-tiles dispatched first (LPT)
  const size_t kqbase = (size_t)bh * (S_LEN * DK);
  const size_t vbase  = (size_t)bh * (DK * S_LEN);
  const int b = bh >> 4, h = bh & 15;
  const int q0w = qt * 64 + rowhalf * 32;

  // Q fragments: B-operand, col=q, k-chunks of 16 over d
  bf16x8 qf[4];
  {
    const ushort* qp = Qb + kqbase + (size_t)(q0w + q) * DK + hi * 8;
#pragma unroll
    for (int kk = 0; kk < 4; ++kk) qf[kk] = *(const bf16x8*)(qp + kk * 16);
  }
  f32x16 oacc[2];
#pragma unroll
  for (int dt = 0; dt < 2; ++dt)
#pragma unroll
    for (int r = 0; r < 16; ++r) oacc[dt][r] = 0.f;
  float m_r = -INFINITY, l_r = 0.f;

  for (int kt = par; kt <= qt; kt += 2) {
    const ushort* kb = Kb + kqbase + (size_t)(kt * 64) * DK;
    const ushort* vb = Vg + vbase + kt * 64;

    // ---- K fragments: 8 x 16B direct loads (L2-hit), issued as a cluster --
    bf16x8 kfr[8];
#pragma unroll
    for (int ct = 0; ct < 2; ++ct)
#pragma unroll
      for (int kk = 0; kk < 4; ++kk)
        kfr[ct * 4 + kk] =
            *(const bf16x8*)(kb + (ct * 32 + q) * DK + (kk * 2 + hi) * 8);

    f32x16 sacc[2];
#pragma unroll
    for (int ct = 0; ct < 2; ++ct)
#pragma unroll
      for (int r = 0; r < 16; ++r) sacc[ct][r] = 0.f;

    __builtin_amdgcn_s_setprio(1);
#pragma unroll
    for (int ct = 0; ct < 2; ++ct)
#pragma unroll
      for (int kk = 0; kk < 4; ++kk)
        sacc[ct] = __builtin_amdgcn_mfma_f32_32x32x16_bf16(
            kfr[ct * 4 + kk], qf[kk], sacc[ct], 0, 0, 0);
    __builtin_amdgcn_s_setprio(0);

    // ---- V fragments: issue now so L2 latency hides under softmax ----
    bf16x8 vfr[8];   // [kc2][dt]
#pragma unroll
    for (int kc2 = 0; kc2 < 4; ++kc2)
#pragma unroll
      for (int dt = 0; dt < 2; ++dt)
        vfr[kc2 * 2 + dt] = *(const bf16x8*)
            (vb + (dt * 32 + q) * S_LEN + (kc2 * 2 + hi) * 8);

    if (kt == qt) {   // causal mask on diagonal tile
#pragma unroll
      for (int r = 0; r < 16; ++r) {
        int crow = (r & 3) + 8 * (r >> 2) + 4 * hi;
        if (rowhalf == 0) {
          if (crow > q) sacc[0][r] = -INFINITY;
          sacc[1][r] = -INFINITY;       // kv 32..63 all above rows 0..31
        } else {
          if (crow > q) sacc[1][r] = -INFINITY;
        }
      }
    }

    // ---- online softmax, exp2 domain, per-lane scalar state ----
    float mx = -INFINITY;
#pragma unroll
    for (int ct = 0; ct < 2; ++ct)
#pragma unroll
      for (int r = 0; r < 16; ++r) mx = fmaxf(mx, sacc[ct][r]);
    mx = fmaxf(mx, __shfl_xor(mx, 32));
    if (mx > m_r + 8.0f) {              // defer-max (log2 units)
      float sc = exp2f(m_r - mx);
      m_r = mx;
      l_r *= sc;
#pragma unroll
      for (int dt = 0; dt < 2; ++dt)
#pragma unroll
        for (int r = 0; r < 16; ++r) oacc[dt][r] *= sc;
    }
    float rs = 0.f;
#pragma unroll
    for (int ct = 0; ct < 2; ++ct)
#pragma unroll
      for (int r = 0; r < 16; ++r) {
        float e = exp2f(sacc[ct][r] - m_r);
        sacc[ct][r] = e;
        rs += e;
      }
    rs += __shfl_xor(rs, 32);
    l_r += rs;

    // ---- PV: P -> bf16 B-fragments in-register (cvt_pk + permlane32) ----
    __builtin_amdgcn_s_setprio(1);
#pragma unroll
    for (int ct = 0; ct < 2; ++ct) {
      uint W8[8];
#pragma unroll
      for (int r4 = 0; r4 < 4; ++r4)
#pragma unroll
        for (int i = 0; i < 2; ++i)
          W8[r4 * 2 + i] = cvt_pk_bf16(sacc[ct][4 * r4 + 2 * i],
                                       sacc[ct][4 * r4 + 2 * i + 1]);
#pragma unroll
      for (int kcl = 0; kcl < 2; ++kcl) {
        uint2v p0 = permswap(W8[4 * kcl],     W8[4 * kcl + 2]);
        uint2v p1 = permswap(W8[4 * kcl + 1], W8[4 * kcl + 3]);
        union { uint u[4]; bf16x8 v; } pb;
        pb.u[0] = p0.x; pb.u[1] = p1.x; pb.u[2] = p0.y; pb.u[3] = p1.y;
        int kc2 = ct * 2 + kcl;
#pragma unroll
        for (int dt = 0; dt < 2; ++dt)
          oacc[dt] = __builtin_amdgcn_mfma_f32_32x32x16_bf16(
              vfr[kc2 * 2 + dt], pb.v, oacc[dt], 0, 0, 0);
      }
    }
    __builtin_amdgcn_s_setprio(0);
  }

  // ---- merge parity partials: waves 2,3 publish; waves 0,1 combine --------
  if (par == 1) {
#pragma unroll
    for (int dt = 0; dt < 2; ++dt)
#pragma unroll
      for (int r = 0; r < 16; ++r) xbuf[rowhalf][lane][dt * 16 + r] = oacc[dt][r];
    xbuf[rowhalf][lane][32] = m_r;
    xbuf[rowhalf][lane][33] = l_r;
  }
  __syncthreads();
  if (par == 0) {
    float mB = xbuf[rowhalf][lane][32];
    float lB = xbuf[rowhalf][lane][33];
    float m2 = fmaxf(m_r, mB);
    float sA = exp2f(m_r - m2);
    float sB = exp2f(mB - m2);
    l_r = l_r * sA + lB * sB;
#pragma unroll
    for (int dt = 0; dt < 2; ++dt)
#pragma unroll
      for (int r = 0; r < 16; ++r)
        oacc[dt][r] = oacc[dt][r] * sA + xbuf[rowhalf][lane][dt * 16 + r] * sB;

    // ---- epilogue: O^T -> O via per-wave LDS transpose, coalesced store ----
    float inv = 1.0f / l_r;
    uint* Ow = (uint*)&oscratch[rowhalf][0];
#pragma unroll
    for (int dt = 0; dt < 2; ++dt)
#pragma unroll
      for (int r4 = 0; r4 < 4; ++r4)
#pragma unroll
        for (int i = 0; i < 2; ++i) {
          int wi = dt * 16 + r4 * 4 + hi * 2 + i;   // = d/2
          uint val = cvt_pk_bf16(oacc[dt][4 * r4 + 2 * i] * inv,
                                 oacc[dt][4 * r4 + 2 * i + 1] * inv);
          Ow[q * 32 + (((wi >> 2) ^ (q & 7)) << 2) + (wi & 3)] = val;
        }
#pragma unroll
    for (int p = 0; p < 4; ++p) {
      int idx2 = p * 64 + lane;
      int qr = idx2 >> 3, c = idx2 & 7;
      bf16x8 v = *(const bf16x8*)
          &((const ushort*)Ow)[qr * 64 + ((c ^ (qr & 7)) << 3)];
      int gq = q0w + qr;
      *(bf16x8*)(Ob + ((size_t)b * S_LEN + gq) * DMODEL + h * DK + c * 8) = v;
    }
  }
}

// ---------------- launcher ----------------
extern "C" void kernel_launch(void* const* d_in, const int* in_sizes, int n_in,
                              void* d_out, int out_size, void* d_ws, size_t ws_size,
                              hipStream_t stream) {
  const float* x  = (const float*)d_in[0];
  const int* pos  = (const int*)d_in[1];
  const float* wq = (const float*)d_in[2];
  const float* wk = (const float*)d_in[3];
  const float* wv = (const float*)d_in[4];
  const float* wo = (const float*)d_in[5];
  float* out = (float*)d_out;

  char* ws = (char*)d_ws;
  ushort* xb    = (ushort*)(ws);                       //  8 MB
  ushort* wqkvb = (ushort*)(ws + (size_t)( 8u << 20)); //  6 MB
  ushort* wob   = (ushort*)(ws + (size_t)(14u << 20)); //  2 MB
  float2* rope  = (float2*)(ws + (size_t)(16u << 20)); //  1 MB
  ushort* Qb    = (ushort*)(ws + (size_t)(17u << 20)); //  8 MB [bh][s][64]
  ushort* Kb    = (ushort*)(ws + (size_t)(25u << 20)); //  8 MB [bh][s][64]
  ushort* Vg    = (ushort*)(ws + (size_t)(33u << 20)); //  8 MB [bh][64][s]  (V^T)
  ushort* Ob    = (ushort*)(ws + (size_t)(41u << 20)); //  8 MB [b][s][d]

  cast_inputs<<<8704, 256, 0, stream>>>((const float4*)x, (const float4*)wq,
      (const float4*)wk, (const float4*)wv, (const float4*)wo,
      (ushort4*)xb, (ushort4*)wqkvb, (ushort4*)wob, pos, rope);
  gemm_bt<0><<<32 * 24, 256, 0, stream>>>(xb, wqkvb, rope, Qb, Kb, Vg, nullptr);
  attn_kernel<<<1024, 256, 0, stream>>>(Qb, Kb, Vg, Ob);
  gemm_bt<1><<<32 * 8, 256, 0, stream>>>(Ob, wob, rope, nullptr, nullptr, nullptr, out);
}

// Round 9
// 124.947 us; speedup vs baseline: 1.3436x; 1.3436x over previous
//
#include <hip/hip_runtime.h>
#include <stdint.h>

#define S_LEN 2048
#define DMODEL 1024
#define NHEAD 16
#define DK 64
#define BATCH 2

typedef __attribute__((ext_vector_type(8))) short bf16x8;
typedef __attribute__((ext_vector_type(4))) float f32x4;

__device__ __forceinline__ unsigned short f2bf(float f) {
  union { float f; unsigned u; } x; x.f = f;
  unsigned u = x.u;
  return (unsigned short)((u + 0x7fffu + ((u >> 16) & 1u)) >> 16);
}

__device__ __forceinline__ uint cvt_pk_bf16(float a, float b) {
  uint r;
  asm("v_cvt_pk_bf16_f32 %0, %1, %2" : "=v"(r) : "v"(a), "v"(b));
  return r;
}

__device__ __forceinline__ void gload_lds16(const void* g, void* l) {
  __builtin_amdgcn_global_load_lds(
      (const __attribute__((address_space(1))) unsigned int*)g,
      (__attribute__((address_space(3))) unsigned int*)l, 16, 0, 0);
}

// Q scale: 1/sqrt(64) * log2(e)  (exp2-domain softmax)
#define QSCALE 0.18033688011112042f

// ------------- cast fp32 -> bf16 (x, weights) + RoPE table (fused) -------
__global__ __launch_bounds__(256) void cast_inputs(
    const float4* __restrict__ x,
    const float4* __restrict__ wq, const float4* __restrict__ wk,
    const float4* __restrict__ wv, const float4* __restrict__ wo,
    ushort4* __restrict__ xb, ushort4* __restrict__ wqkvb, ushort4* __restrict__ wob,
    const int* __restrict__ pos, float2* __restrict__ rope)
{
  int i = blockIdx.x * 256 + threadIdx.x;
  const int NCAST = (1 << 21);
  if (i < NCAST) {
    float4 v; ushort4* dst;
    if (i < (1 << 20)) {
      v = x[i]; dst = xb + i;
    } else {
      int j = i - (1 << 20);
      int wsel = j >> 18;
      int o = j & ((1 << 18) - 1);
      const float4* src = (wsel == 0) ? wq : (wsel == 1) ? wk : (wsel == 2) ? wv : wo;
      v = src[o];
      dst = (wsel < 3) ? (wqkvb + ((size_t)wsel << 18) + o) : (wob + o);
    }
    ushort4 r;
    r.x = f2bf(v.x); r.y = f2bf(v.y); r.z = f2bf(v.z); r.w = f2bf(v.w);
    *dst = r;
  } else {
    int idx = i - NCAST;
    if (idx < 4096 * 32) {
      int ps = idx >> 5;
      int fi = idx & 31;
      float p = (float)pos[ps];
      float freq = exp2f(-(float)fi * 0.41524101186092096f);
      float ang = p * freq;
      rope[idx] = make_float2(cosf(ang), sinf(ang));
    }
  }
}

// ---------------- GEMM (bf16 in, fp32 acc), B^T weights -------------------
template<int EPI>
__global__ __launch_bounds__(256) void gemm_bt(
    const ushort* __restrict__ A, const ushort* __restrict__ Bw,
    const float2* __restrict__ rope,
    ushort* __restrict__ Qb, ushort* __restrict__ Kb, ushort* __restrict__ Vg,
    float* __restrict__ Out)
{
  constexpr int Kdim = 1024;
  __shared__ ushort At[128 * 64];
  __shared__ ushort Bt[128 * 64];
  const int bm = blockIdx.x & 31;
  const int bn = blockIdx.x >> 5;
  const int tid = threadIdx.x;
  const int w = tid >> 6, lane = tid & 63;
  const int wr = w >> 1, wc = w & 1;
  const int lrow = lane >> 3;
  const int lch = lane & 7;

  f32x4 acc[4][4];
#pragma unroll
  for (int i = 0; i < 4; ++i)
#pragma unroll
    for (int j = 0; j < 4; ++j) acc[i][j] = (f32x4){0.f, 0.f, 0.f, 0.f};

  const size_t abase = (size_t)(bm * 128) * Kdim;
  const size_t bbase = (size_t)(bn * 128) * Kdim;

  for (int kt = 0; kt < Kdim / 64; ++kt) {
#pragma unroll
    for (int inst = 0; inst < 4; ++inst) {
      int r = w * 32 + inst * 8 + lrow;
      int gc = lch ^ (r & 7);
      gload_lds16(A + abase + (size_t)r * Kdim + kt * 64 + gc * 8,
                  &At[(w * 32 + inst * 8) * 64]);
      gload_lds16(Bw + bbase + (size_t)r * Kdim + kt * 64 + gc * 8,
                  &Bt[(w * 32 + inst * 8) * 64]);
    }
    __syncthreads();
    __builtin_amdgcn_s_setprio(1);
#pragma unroll
    for (int kk = 0; kk < 2; ++kk) {
      bf16x8 af[4], bfv[4];
      int ch = kk * 4 + (lane >> 4);
#pragma unroll
      for (int fm = 0; fm < 4; ++fm) {
        int row = wr * 64 + fm * 16 + (lane & 15);
        af[fm] = *(const bf16x8*)&At[row * 64 + ((ch ^ (row & 7)) << 3)];
      }
#pragma unroll
      for (int fn = 0; fn < 4; ++fn) {
        int row = wc * 64 + fn * 16 + (lane & 15);
        bfv[fn] = *(const bf16x8*)&Bt[row * 64 + ((ch ^ (row & 7)) << 3)];
      }
#pragma unroll
      for (int fm = 0; fm < 4; ++fm)
#pragma unroll
        for (int fn = 0; fn < 4; ++fn)
          acc[fm][fn] = __builtin_amdgcn_mfma_f32_16x16x32_bf16(
              af[fm], bfv[fn], acc[fm][fn], 0, 0, 0);
    }
    __builtin_amdgcn_s_setprio(0);
    __syncthreads();
  }

  if constexpr (EPI == 0) {
    const int sel = bn >> 3;            // 0=Q 1=K 2=V (block-uniform)
    if (sel == 2) {
      // V: transposed global layout [bh][d][s]
#pragma unroll
      for (int fn = 0; fn < 4; ++fn) {
        int gn = bn * 128 + wc * 64 + fn * 16 + (lane & 15);
        int col = gn & 1023;
        int h = col >> 6, d = col & 63;
#pragma unroll
        for (int fm = 0; fm < 4; ++fm) {
          int gm0 = bm * 128 + wr * 64 + fm * 16 + ((lane >> 4) << 2);
          int b = gm0 >> 11, s0 = gm0 & 2047;
          uint lo = cvt_pk_bf16(acc[fm][fn][0], acc[fm][fn][1]);
          uint hi2 = cvt_pk_bf16(acc[fm][fn][2], acc[fm][fn][3]);
          uint2 val; val.x = lo; val.y = hi2;
          *(uint2*)(Vg + ((size_t)((b * NHEAD + h) * DK + d) * S_LEN) + s0) = val;
        }
      }
    } else {
      ushort* dst0 = (sel == 0) ? Qb : Kb;
#pragma unroll
      for (int fn = 0; fn < 4; ++fn) {
        int gn = bn * 128 + wc * 64 + fn * 16 + (lane & 15);
        int col = gn & 1023;
        int h = col >> 6, d = col & 63;
#pragma unroll
        for (int fm = 0; fm < 4; ++fm) {
          int gm0 = bm * 128 + wr * 64 + fm * 16 + ((lane >> 4) << 2);
#pragma unroll
          for (int j = 0; j < 4; ++j) {
            int gm = gm0 + j;
            float v = acc[fm][fn][j];
            float p = __shfl_xor(v, 1);
            float2 cs = rope[gm * 32 + (d >> 1)];
            float r = (d & 1) ? (v * cs.x + p * cs.y) : (v * cs.x - p * cs.y);
            if (sel == 0) r *= QSCALE;  // 1/8 * log2(e): exp2-domain softmax
            int b = gm >> 11, s = gm & 2047;
            dst0[((size_t)(b * NHEAD + h) * S_LEN + s) * DK + d] = f2bf(r);
          }
        }
      }
    }
  } else {
#pragma unroll
    for (int fn = 0; fn < 4; ++fn) {
      int gn = bn * 128 + wc * 64 + fn * 16 + (lane & 15);
#pragma unroll
      for (int fm = 0; fm < 4; ++fm) {
        int gm0 = bm * 128 + wr * 64 + fm * 16 + ((lane >> 4) << 2);
#pragma unroll
        for (int j = 0; j < 4; ++j)
          Out[(size_t)(gm0 + j) * 1024 + gn] = acc[fm][fn][j];
      }
    }
  }
}

// ---------------- causal flash attention, swapped-QK^T, bf16 MFMA ----------
// RESTORED Round-1 structure (measured 55.5 us): grid 512 = 32 bh * 16 pairs;
// block 256 = 4 waves, wave w owns q-rows [qt*64+w*16, +16). Block processes
// q-tiles {pair, 31-pair} sequentially -> exactly 33 kv-tiles (balanced).
// Only edits vs Round-1: exp2f softmax (QSCALE carries log2e), cvt_pk packs.
__global__ __launch_bounds__(256) void attn_kernel(
    const ushort* __restrict__ Qb, const ushort* __restrict__ Kb,
    const ushort* __restrict__ Vg, ushort* __restrict__ Ob)
{
  __shared__ ushort Kt[2][64 * 64];     // [kv][d] swizzled, double-buffered
  __shared__ ushort Vt[2][64 * 64];     // [d][kv] swizzled (from global V^T)
  __shared__ ushort Pt[4][16 * 64];     // per-wave P buffer [q][kv] swizzled
  const int tid = threadIdx.x;
  const int w = tid >> 6, lane = tid & 63;
  const int g = lane >> 4, q = lane & 15;
  const int bid = blockIdx.x;
  const int swz = (bid & 7) * 64 + (bid >> 3);   // XCD-chunked: same-bh together
  const int bh = swz >> 4, pair = swz & 15;
  const size_t kqbase = (size_t)bh * (S_LEN * DK);  // Q,K: [s][64]
  const size_t vbase  = (size_t)bh * (DK * S_LEN);  // V^T: [64][2048]
  const int b = bh >> 4, h = bh & 15;
  ushort* Pw = Pt[w];
  uint* Pw32 = (uint*)Pw;

  for (int t2 = 0; t2 < 2; ++t2) {
    const int qt = t2 ? (31 - pair) : pair;
    const int qrow0 = qt * 64 + w * 16;

    bf16x8 qf[2];
    {
      const ushort* qp = Qb + kqbase + (size_t)(qrow0 + q) * DK + g * 8;
      qf[0] = *(const bf16x8*)qp;
      qf[1] = *(const bf16x8*)(qp + 32);
    }
    f32x4 oacc[4];
#pragma unroll
    for (int dt = 0; dt < 4; ++dt) oacc[dt] = (f32x4){0.f, 0.f, 0.f, 0.f};
    float m_r = -INFINITY, l_r = 0.f;

    // ---- stage tile 0 into buffer 0 ----
#pragma unroll
    for (int pass = 0; pass < 2; ++pass) {
      int r0 = pass * 32 + w * 8;
      int r = r0 + (lane >> 3);
      int gc = (lane & 7) ^ (r & 7);
      gload_lds16(Kb + kqbase + (size_t)r * DK + gc * 8, &Kt[0][r0 * 64]);
      gload_lds16(Vg + vbase + (size_t)r * S_LEN + gc * 8, &Vt[0][r0 * 64]);
    }
    __syncthreads();

    int cur = 0;
    for (int kt = 0; kt <= qt; ++kt) {
      // ---- prefetch next tile into other buffer (overlaps compute) ----
      if (kt < qt) {
        int nxt = cur ^ 1, ktn = kt + 1;
#pragma unroll
        for (int pass = 0; pass < 2; ++pass) {
          int r0 = pass * 32 + w * 8;
          int r = r0 + (lane >> 3);
          int gc = (lane & 7) ^ (r & 7);
          gload_lds16(Kb + kqbase + (size_t)(ktn * 64 + r) * DK + gc * 8,
                      &Kt[nxt][r0 * 64]);
          gload_lds16(Vg + vbase + (size_t)r * S_LEN + ktn * 64 + gc * 8,
                      &Vt[nxt][r0 * 64]);
        }
      }

      // ---- S^T = K Q^T : lane owns column q (one q-row of S) ----
      f32x4 sacc[4];
#pragma unroll
      for (int ct = 0; ct < 4; ++ct) sacc[ct] = (f32x4){0.f, 0.f, 0.f, 0.f};
      __builtin_amdgcn_s_setprio(1);
#pragma unroll
      for (int kk = 0; kk < 2; ++kk) {
        int ch = kk * 4 + g;
#pragma unroll
        for (int ct = 0; ct < 4; ++ct) {
          int row = ct * 16 + q;
          bf16x8 kf = *(const bf16x8*)&Kt[cur][row * 64 + ((ch ^ (row & 7)) << 3)];
          sacc[ct] = __builtin_amdgcn_mfma_f32_16x16x32_bf16(kf, qf[kk], sacc[ct], 0, 0, 0);
        }
      }
      __builtin_amdgcn_s_setprio(0);

      if (kt == qt) {                   // causal mask on diagonal tile
        int qa = qrow0 + q;
#pragma unroll
        for (int ct = 0; ct < 4; ++ct) {
#pragma unroll
          for (int j = 0; j < 4; ++j) {
            int kv = qt * 64 + ct * 16 + g * 4 + j;
            if (kv > qa) sacc[ct][j] = -INFINITY;
          }
        }
      }

      // ---- online softmax: per-lane scalar state (lane owns one q-row) ----
      float mx = sacc[0][0];
#pragma unroll
      for (int ct = 0; ct < 4; ++ct)
#pragma unroll
        for (int j = 0; j < 4; ++j) mx = fmaxf(mx, sacc[ct][j]);
      mx = fmaxf(mx, __shfl_xor(mx, 16));
      mx = fmaxf(mx, __shfl_xor(mx, 32));
      if (mx > m_r + 8.0f) {            // defer-max: rescale only on growth
        float sc = exp2f(m_r - mx);
        m_r = mx;
        l_r *= sc;
#pragma unroll
        for (int dt = 0; dt < 4; ++dt)
#pragma unroll
          for (int j = 0; j < 4; ++j) oacc[dt][j] *= sc;
      }
      float p[4][4];
      float rs = 0.f;
#pragma unroll
      for (int ct = 0; ct < 4; ++ct)
#pragma unroll
        for (int j = 0; j < 4; ++j) {
          float e = exp2f(sacc[ct][j] - m_r);
          p[ct][j] = e; rs += e;
        }
      rs += __shfl_xor(rs, 16);
      rs += __shfl_xor(rs, 32);
      l_r += rs;

      // ---- P^T -> per-wave LDS (packed bf16 pairs along kv), reload as
      //      PV B-fragments (col=q, k-walk along kv) ----
#pragma unroll
      for (int ct = 0; ct < 4; ++ct)
#pragma unroll
        for (int i = 0; i < 2; ++i) {
          uint u = cvt_pk_bf16(p[ct][2 * i], p[ct][2 * i + 1]);
          int idx = 8 * ct + 2 * g + i;            // = kv/2
          Pw32[q * 32 + (((idx >> 2) ^ (q & 7)) << 2) + (idx & 3)] = u;
        }
      __builtin_amdgcn_s_setprio(1);
#pragma unroll
      for (int kk = 0; kk < 2; ++kk) {
        int ch = kk * 4 + g;
        bf16x8 pb = *(const bf16x8*)&Pw[q * 64 + ((ch ^ (q & 7)) << 3)];
#pragma unroll
        for (int dt = 0; dt < 4; ++dt) {
          int vr = dt * 16 + q;
          bf16x8 vf = *(const bf16x8*)&Vt[cur][vr * 64 + ((ch ^ (vr & 7)) << 3)];
          oacc[dt] = __builtin_amdgcn_mfma_f32_16x16x32_bf16(vf, pb, oacc[dt], 0, 0, 0);
        }
      }
      __builtin_amdgcn_s_setprio(0);
      __syncthreads();                  // drains prefetch vmcnt + buffer handoff
      cur ^= 1;
    }

    // ---- epilogue: O^T/l -> bf16, transpose via per-wave LDS, coalesced store
    float inv = 1.0f / l_r;
#pragma unroll
    for (int dt = 0; dt < 4; ++dt)
#pragma unroll
      for (int i = 0; i < 2; ++i) {
        uint u = cvt_pk_bf16(oacc[dt][2 * i] * inv, oacc[dt][2 * i + 1] * inv);
        int idx = dt * 8 + 2 * g + i;              // = d/2
        Pw32[q * 32 + (((idx >> 2) ^ (q & 7)) << 2) + (idx & 3)] = u;
      }
#pragma unroll
    for (int pass = 0; pass < 2; ++pass) {
      int qr = pass * 8 + (lane >> 3), c = lane & 7;
      bf16x8 vv = *(const bf16x8*)&Pw[qr * 64 + ((c ^ (qr & 7)) << 3)];
      *(bf16x8*)(Ob + ((size_t)(b * S_LEN) + qrow0 + qr) * DMODEL + h * DK + c * 8) = vv;
    }
  }
}

// ---------------- launcher ----------------
extern "C" void kernel_launch(void* const* d_in, const int* in_sizes, int n_in,
                              void* d_out, int out_size, void* d_ws, size_t ws_size,
                              hipStream_t stream) {
  const float* x  = (const float*)d_in[0];
  const int* pos  = (const int*)d_in[1];
  const float* wq = (const float*)d_in[2];
  const float* wk = (const float*)d_in[3];
  const float* wv = (const float*)d_in[4];
  const float* wo = (const float*)d_in[5];
  float* out = (float*)d_out;

  char* ws = (char*)d_ws;
  ushort* xb    = (ushort*)(ws);                       //  8 MB
  ushort* wqkvb = (ushort*)(ws + (size_t)( 8u << 20)); //  6 MB
  ushort* wob   = (ushort*)(ws + (size_t)(14u << 20)); //  2 MB
  float2* rope  = (float2*)(ws + (size_t)(16u << 20)); //  1 MB
  ushort* Qb    = (ushort*)(ws + (size_t)(17u << 20)); //  8 MB [bh][s][64]
  ushort* Kb    = (ushort*)(ws + (size_t)(25u << 20)); //  8 MB [bh][s][64]
  ushort* Vg    = (ushort*)(ws + (size_t)(33u << 20)); //  8 MB [bh][64][s]  (V^T)
  ushort* Ob    = (ushort*)(ws + (size_t)(41u << 20)); //  8 MB [b][s][d]

  cast_inputs<<<8704, 256, 0, stream>>>((const float4*)x, (const float4*)wq,
      (const float4*)wk, (const float4*)wv, (const float4*)wo,
      (ushort4*)xb, (ushort4*)wqkvb, (ushort4*)wob, pos, rope);
  gemm_bt<0><<<32 * 24, 256, 0, stream>>>(xb, wqkvb, rope, Qb, Kb, Vg, nullptr);
  attn_kernel<<<512, 256, 0, stream>>>(Qb, Kb, Vg, Ob);
  gemm_bt<1><<<32 * 8, 256, 0, stream>>>(Ob, wob, rope, nullptr, nullptr, nullptr, out);
}